// Round 1
// baseline (114.133 us; speedup 1.0000x reference)
//
#include <hip/hip_runtime.h>

// ScatterND (k=1): out = data.copy(); out[indices[i]] = updates[i]
// data:    [1000000, 64] f32
// indices: [100000, 1]   i32
// updates: [100000, 64]  f32
// out:     [1000000, 64] f32
//
// Memory-bound. Pass 1: vectorized float4 copy of data -> out (512 MB traffic).
// Pass 2: vectorized float4 scatter of updates into out (52 MB traffic).
// Stream ordering serializes the two kernels, so no race on updated rows.

__global__ void scatternd_copy_kernel(const float4* __restrict__ src,
                                      float4* __restrict__ dst,
                                      size_t n4) {
    size_t i = (size_t)blockIdx.x * blockDim.x + threadIdx.x;
    const size_t stride = (size_t)gridDim.x * blockDim.x;
    for (; i < n4; i += stride) {
        dst[i] = src[i];
    }
}

__global__ void scatternd_scatter_kernel(const int* __restrict__ idx,
                                         const float4* __restrict__ upd,
                                         float4* __restrict__ out,
                                         size_t total4) {
    // Each row of updates is 64 floats = 16 float4. Thread i handles
    // float4 #(i & 15) of update-row #(i >> 4). The 16 threads sharing a row
    // load the same index (L1-broadcast).
    size_t i = (size_t)blockIdx.x * blockDim.x + threadIdx.x;
    const size_t stride = (size_t)gridDim.x * blockDim.x;
    for (; i < total4; i += stride) {
        const size_t row = i >> 4;
        const size_t col = i & 15;
        const int r = idx[row];
        out[(size_t)r * 16 + col] = upd[i];
    }
}

extern "C" void kernel_launch(void* const* d_in, const int* in_sizes, int n_in,
                              void* d_out, int out_size, void* d_ws, size_t ws_size,
                              hipStream_t stream) {
    const float* data    = (const float*)d_in[0];
    const int*   indices = (const int*)d_in[1];
    const float* updates = (const float*)d_in[2];
    float* out = (float*)d_out;

    const size_t n4 = (size_t)out_size / 4;            // 16M float4 (out_size = 64M)
    const size_t num_updates = (size_t)in_sizes[1];    // 100000 (indices flat count, k=1)
    const size_t total4 = num_updates * 16;            // 1.6M float4

    const int block = 256;
    // Grid-stride, capped at 2048 blocks (256 CU x 8 blocks/CU).
    int grid_copy = (int)((n4 + block - 1) / block);
    if (grid_copy > 2048) grid_copy = 2048;
    int grid_scat = (int)((total4 + block - 1) / block);
    if (grid_scat > 2048) grid_scat = 2048;

    scatternd_copy_kernel<<<grid_copy, block, 0, stream>>>(
        (const float4*)data, (float4*)out, n4);
    scatternd_scatter_kernel<<<grid_scat, block, 0, stream>>>(
        indices, (const float4*)updates, (float4*)out, total4);
}